// Round 16
// baseline (132.123 us; speedup 1.0000x reference)
//
#include <hip/hip_runtime.h>
#include <cfloat>
#include <cstddef>
#include <cstdint>

#define BATCH 8
#define CDIM  256
#define NTOK  2304   // 48*48

typedef float    f32x4  __attribute__((ext_vector_type(4)));
typedef float    f32x16 __attribute__((ext_vector_type(16)));
typedef _Float16 f16x8  __attribute__((ext_vector_type(8)));
typedef _Float16 f16x4  __attribute__((ext_vector_type(4)));

#define MFMA16(a, b, c) __builtin_amdgcn_mfma_f32_16x16x32_f16(a, b, c, 0, 0, 0)
#define MFMA32(a, b, c) __builtin_amdgcn_mfma_f32_32x32x16_f16(a, b, c, 0, 0, 0)

__device__ __forceinline__ void gl_lds16(const void* g, void* l) {
    __builtin_amdgcn_global_load_lds(
        (const __attribute__((address_space(1))) void*)g,
        (__attribute__((address_space(3))) void*)l, 16, 0, 0);
}

// ---------------------------------------------------------------------------
// cast_w: Wq|Wk|Wv fp32 -> Wh fp16 [3][256][256]  (W only; X cast fused into
// proj_mfma)
// ---------------------------------------------------------------------------
__global__ __launch_bounds__(256) void cast_w(
    const float* __restrict__ Wq, const float* __restrict__ Wk,
    const float* __restrict__ Wv, _Float16* __restrict__ Wh)
{
    int i = (blockIdx.x * 256 + threadIdx.x) * 4;
    const float* src = (i < 65536) ? (Wq + i)
                     : (i < 131072) ? (Wk + (i - 65536)) : (Wv + (i - 131072));
    float4 v = *(const float4*)src;
    f16x4 h = { (_Float16)v.x, (_Float16)v.y, (_Float16)v.z, (_Float16)v.w };
    *(f16x4*)(Wh + i) = h;
}

// ---------------------------------------------------------------------------
// proj_mfma v2 — X cast+transpose FUSED (no Xt roundtrip).
// Per c-chunk of 64: stage W (gl_lds16, fp16) and X (fp32 global -> cvt ->
// T16 -> LDS-transpose -> Xl chunk region, absolute-chunk swizzle identical
// to the verified layout). MFMA loop and epilogues byte-identical to r12-r14.
// LDS: Xl 32KB + Wl 32KB + T16 9KB = 73.2KB -> 2 blocks/CU.
// ---------------------------------------------------------------------------
__global__ __launch_bounds__(256, 2) void proj_mfma(
    const float* __restrict__ x1, const float* __restrict__ x2,
    const _Float16* __restrict__ Wh,
    const float* __restrict__ bq, const float* __restrict__ bk,
    const float* __restrict__ bv,
    _Float16* __restrict__ Qo, _Float16* __restrict__ Ko, _Float16* __restrict__ Vo)
{
    const int tid  = threadIdx.x;
    const int lane = tid & 63;
    const int w    = tid >> 6;
    const int l15  = lane & 15, l4 = lane >> 4;
    const int n0   = blockIdx.x * 64;
    const int mode = blockIdx.y;
    const int b    = blockIdx.z;

    const float* X     = (mode == 0) ? x1 : x2;
    const _Float16* Wm = Wh + mode * 65536;
    const float* bias  = (mode == 0) ? bq : (mode == 1) ? bk : bv;
    _Float16* OUT      = (mode == 0) ? Qo : (mode == 1) ? Ko : Vo;

    __shared__ __align__(16) char sm[74752];
    _Float16* Xl  = (_Float16*)sm;             // [64 n][256 c] swizzled, 32KB
    _Float16* Wl  = (_Float16*)(sm + 32768);   // [256 o][64 c] swizzled, 32KB
    _Float16* T16 = (_Float16*)(sm + 65536);   // [64 c][72 n] transpose stage

    float bias_o[4];
#pragma unroll
    for (int ot = 0; ot < 4; ++ot) bias_o[ot] = bias[w * 64 + ot * 16 + l15];

    f32x4 acc[16];
#pragma unroll
    for (int i = 0; i < 16; ++i) acc[i] = (f32x4){0.f, 0.f, 0.f, 0.f};

    for (int c0 = 0; c0 < CDIM; c0 += 64) {
        __syncthreads();   // previous chunk fully consumed (Wl / T16 / Xl-chunk)

        // ---- stage W chunk [256 o][64 c] via gl_lds16 (verified path) ----
#pragma unroll
        for (int t = 0; t < 8; ++t) {
            int i = w * 8 + t;
            int row = 8 * i + (lane >> 3);
            int ch  = lane & 7;
            gl_lds16(Wm + (size_t)row * CDIM + c0 + ((ch ^ (row & 7)) * 8),
                     (char*)Wl + i * 1024);
        }

        // ---- X fp32 tile [64 c][64 n]: load + cast -> T16 ----
        {
            const int cl = tid >> 2, ngb = (tid & 3) * 16;
            const float* src = X + (size_t)(b * CDIM + c0 + cl) * NTOK + n0 + ngb;
            f16x8 h0, h1;
#pragma unroll
            for (int u = 0; u < 2; ++u) {
                float4 va = *(const float4*)(src + u * 8);
                float4 vb = *(const float4*)(src + u * 8 + 4);
                f16x8& h = u ? h1 : h0;
                h[0] = (_Float16)va.x; h[1] = (_Float16)va.y;
                h[2] = (_Float16)va.z; h[3] = (_Float16)va.w;
                h[4] = (_Float16)vb.x; h[5] = (_Float16)vb.y;
                h[6] = (_Float16)vb.z; h[7] = (_Float16)vb.w;
            }
            *(f16x8*)&T16[cl * 72 + ngb]     = h0;
            *(f16x8*)&T16[cl * 72 + ngb + 8] = h1;
        }
        __syncthreads();   // T16 ready

        // ---- transpose T16 -> Xl chunk region (absolute-chunk swizzle) ----
        {
            const int nl = tid >> 2, cgb = (tid & 3) * 16;
            f16x8 o0, o1;
#pragma unroll
            for (int i = 0; i < 8; ++i) {
                o0[i] = T16[(cgb + i) * 72 + nl];
                o1[i] = T16[(cgb + 8 + i) * 72 + nl];
            }
            const int ch0 = (c0 + cgb) >> 3;   // absolute 16B-chunk index
            *(f16x8*)((char*)Xl + nl * 512 + ((ch0 ^ (nl & 7)) * 16))       = o0;
            *(f16x8*)((char*)Xl + nl * 512 + (((ch0 + 1) ^ (nl & 7)) * 16)) = o1;
        }
        __syncthreads();   // Xl chunk + Wl ready (vmcnt drained by barrier)

        // ---- MFMA over this c-chunk (byte-identical to verified loop) ----
#pragma unroll
        for (int kk2 = 0; kk2 < 2; ++kk2) {
            f16x8 a[4], bf[4];
#pragma unroll
            for (int nt = 0; nt < 4; ++nt) {
                int row = nt * 16 + l15;
                int ch  = ((c0 >> 3) + kk2 * 4 + l4) ^ (row & 7);
                a[nt] = *(const f16x8*)((const char*)Xl + row * 512 + ch * 16);
            }
#pragma unroll
            for (int ot = 0; ot < 4; ++ot) {
                int row = w * 64 + ot * 16 + l15;
                int ch  = (kk2 * 4 + l4) ^ (row & 7);
                bf[ot] = *(const f16x8*)((const char*)Wl + row * 128 + ch * 16);
            }
#pragma unroll
            for (int nt = 0; nt < 4; ++nt)
#pragma unroll
                for (int ot = 0; ot < 4; ++ot)
                    acc[nt * 4 + ot] = MFMA16(a[nt], bf[ot], acc[nt * 4 + ot]);
        }
    }

    __syncthreads();

    if (mode <= 1) {
        _Float16* Dl = (_Float16*)sm;
#pragma unroll
        for (int nt = 0; nt < 4; ++nt)
#pragma unroll
            for (int ot = 0; ot < 4; ++ot)
#pragma unroll
                for (int reg = 0; reg < 4; ++reg)
                    Dl[(nt * 16 + 4 * l4 + reg) * 256 + w * 64 + ot * 16 + l15] =
                        (_Float16)(acc[nt * 4 + ot][reg] + bias_o[ot]);
        __syncthreads();
        char* dst = (char*)(OUT + ((size_t)b * NTOK + n0) * CDIM);
#pragma unroll
        for (int u = 0; u < 8; ++u) {
            f16x8 v = *(const f16x8*)((const char*)Dl + u * 4096 + tid * 16);
            *(f16x8*)(dst + u * 4096 + tid * 16) = v;
        }
    } else {
        _Float16* Dlv = (_Float16*)sm;   // [256][80]
#pragma unroll
        for (int nt = 0; nt < 4; ++nt)
#pragma unroll
            for (int ot = 0; ot < 4; ++ot)
#pragma unroll
                for (int reg = 0; reg < 4; ++reg)
                    Dlv[(w * 64 + ot * 16 + l15) * 80 + nt * 16 + 4 * l4 + reg] =
                        (_Float16)(acc[nt * 4 + ot][reg] + bias_o[ot]);
        __syncthreads();
#pragma unroll
        for (int t = 0; t < 8; ++t) {
            int ro = (w * 8 + t) * 8 + (lane >> 3);
            f16x8 v = *(const f16x8*)((const char*)Dlv + ro * 160 + (lane & 7) * 16);
            *(f16x8*)(OUT + ((size_t)b * CDIM + ro) * NTOK + n0 + (lane & 7) * 8) = v;
        }
    }
}

// ---------------------------------------------------------------------------
// Split-KV flash attention — UNCHANGED from r14 (verified 78.5us):
// 32x32x16 swapped-operand, sigma K-row perm, no P LDS, precomputed staging
// pointers, jb not unrolled, KVBLK=64 dbuf, 128KB LDS.
// ---------------------------------------------------------------------------
template <int SEG>
__global__ __launch_bounds__(512, 2) void attn_fa(
    const _Float16* __restrict__ Q, const _Float16* __restrict__ K,
    const _Float16* __restrict__ Vt, _Float16* __restrict__ pacc,
    float2* __restrict__ pml)
{
    const int tid  = threadIdx.x;
    const int lane = tid & 63;
    const int w    = tid >> 6;
    const int l31  = lane & 31;
    const int h    = lane >> 5;

    const int nb  = 9 * BATCH * SEG, cpx = nb / 8;
    const int bid = blockIdx.x;
    const int swz = (bid & 7) * cpx + (bid >> 3);
    const int x = swz % 9;
    const int b = (swz / 9) & 7;
    const int z = swz / 72;

    const int row0   = x * 256 + w * 32;
    const int jbase  = z * (NTOK / SEG);
    const int NTILES = NTOK / SEG / 64;

    __shared__ __align__(16) char smem[131072];

    const _Float16* kSrc0; const _Float16* kSrc1;
    const _Float16* kSrc2; const _Float16* kSrc3;
    const _Float16* vSrc0; const _Float16* vSrc1;
    const _Float16* vSrc2; const _Float16* vSrc3;
    {
        const size_t kbb = (size_t)b * NTOK;
        const size_t vbb = (size_t)b * CDIM * NTOK;
        const int chunk = lane & 31;
        const int vch   = lane & 7;
        const int vr    = lane >> 3;
#pragma unroll
        for (int t = 0; t < 4; ++t) {
            int i  = w * 4 + t;
            int lr = 2 * i + h;
            int gr = (lr & 51) | ((lr & 4) << 1) | ((lr & 8) >> 1);
            const _Float16* ks =
                K + (kbb + jbase + gr) * CDIM + ((chunk ^ (lr & 7)) * 8);
            int vrow = 8 * i + vr;
            const _Float16* vs =
                Vt + vbb + (size_t)vrow * NTOK + jbase + ((vch ^ (vrow & 7)) * 8);
            if (t == 0) { kSrc0 = ks; vSrc0 = vs; }
            else if (t == 1) { kSrc1 = ks; vSrc1 = vs; }
            else if (t == 2) { kSrc2 = ks; vSrc2 = vs; }
            else { kSrc3 = ks; vSrc3 = vs; }
        }
    }

    f16x8 qa[16];
    {
        const _Float16* qb = Q + ((size_t)b * NTOK + row0 + l31) * CDIM + h * 8;
#pragma unroll
        for (int kk = 0; kk < 16; ++kk)
            qa[kk] = __builtin_nontemporal_load((const f16x8*)(qb + kk * 16));
    }

    f32x16 acc[8];
#pragma unroll
    for (int cb = 0; cb < 8; ++cb)
#pragma unroll
        for (int e = 0; e < 16; ++e) acc[cb][e] = 0.f;
    float m  = -FLT_MAX;
    float ps = 0.f;

    const int ldsDstK = w * 4096;
    const int ldsDstV = 32768 + w * 4096;

    auto stage = [&](int buf) {
        char* base = smem + buf * 65536;
        gl_lds16(kSrc0, base + ldsDstK);
        gl_lds16(kSrc1, base + ldsDstK + 1024);
        gl_lds16(kSrc2, base + ldsDstK + 2048);
        gl_lds16(kSrc3, base + ldsDstK + 3072);
        gl_lds16(vSrc0, base + ldsDstV);
        gl_lds16(vSrc1, base + ldsDstV + 1024);
        gl_lds16(vSrc2, base + ldsDstV + 2048);
        gl_lds16(vSrc3, base + ldsDstV + 3072);
        kSrc0 += 64 * CDIM; kSrc1 += 64 * CDIM;
        kSrc2 += 64 * CDIM; kSrc3 += 64 * CDIM;
        vSrc0 += 64; vSrc1 += 64; vSrc2 += 64; vSrc3 += 64;
    };

    stage(0);
    __syncthreads();

    const int xs = l31 & 7;

    for (int jt = 0; jt < NTILES; ++jt) {
        const int cur = jt & 1;

        if (jt + 1 < NTILES) stage(cur ^ 1);

        const char* Klc = (const char*)smem + cur * 65536;
        const char* Vlc = Klc + 32768;

#pragma unroll 1
        for (int jb = 0; jb < 2; ++jb) {
            f32x16 s;
#pragma unroll
            for (int e = 0; e < 16; ++e) s[e] = 0.f;
            const char* kb = Klc + (jb * 32 + l31) * 512;
#pragma unroll
            for (int kk = 0; kk < 16; ++kk) {
                f16x8 kf = *(const f16x8*)(kb + (((kk * 2 + h) ^ xs) * 16));
                s = MFMA32(kf, qa[kk], s);
            }

            float pm = s[0];
#pragma unroll
            for (int e = 1; e < 16; ++e) pm = fmaxf(pm, s[e]);
            pm = fmaxf(pm, __shfl_xor(pm, 32));
            if (pm > m + 8.f) {
                float sc = __expf(m - pm);
                m = pm;
                ps *= sc;
#pragma unroll
                for (int cb = 0; cb < 8; ++cb)
#pragma unroll
                    for (int e = 0; e < 16; ++e) acc[cb][e] *= sc;
            }

            f16x8 pa0, pa1;
#pragma unroll
            for (int e = 0; e < 8; ++e) {
                float p0 = __expf(s[e] - m);
                float p1 = __expf(s[8 + e] - m);
                ps += p0 + p1;
                pa0[e] = (_Float16)p0;
                pa1[e] = (_Float16)p1;
            }

            const int o0 = ((jb * 4 + 0 + h) ^ xs) * 16;
            const int o1 = ((jb * 4 + 2 + h) ^ xs) * 16;
#pragma unroll
            for (int cb = 0; cb < 8; ++cb) {
                const char* vb0 = Vlc + (cb * 32 + l31) * 128;
                f16x8 v0 = *(const f16x8*)(vb0 + o0);
                acc[cb] = MFMA32(v0, pa0, acc[cb]);
                f16x8 v1 = *(const f16x8*)(vb0 + o1);
                acc[cb] = MFMA32(v1, pa1, acc[cb]);
            }
        }

        __syncthreads();
    }

    float l_full = ps + __shfl_xor(ps, 32);
    float inv = 1.f / l_full;
    const size_t pbase = ((size_t)z * BATCH + b) * NTOK * CDIM;
    _Float16* stg = (_Float16*)(smem + w * 8448);

#pragma unroll
    for (int pass = 0; pass < 2; ++pass) {
#pragma unroll
        for (int cb4 = 0; cb4 < 4; ++cb4) {
            const f32x16 a = acc[pass * 4 + cb4];
#pragma unroll
            for (int g = 0; g < 4; ++g) {
                f16x4 o = { (_Float16)(a[4 * g + 0] * inv),
                            (_Float16)(a[4 * g + 1] * inv),
                            (_Float16)(a[4 * g + 2] * inv),
                            (_Float16)(a[4 * g + 3] * inv) };
                *(f16x4*)&stg[l31 * 132 + cb4 * 32 + g * 8 + h * 4] = o;
            }
        }
        asm volatile("s_waitcnt lgkmcnt(0)" ::: "memory");
        __builtin_amdgcn_sched_barrier(0);
        {
            char* dst = (char*)(pacc + pbase + (size_t)row0 * CDIM) + pass * 256;
#pragma unroll
            for (int u = 0; u < 8; ++u) {
                int r = u * 4 + (lane >> 4);
                f16x8 v = *(const f16x8*)((const char*)stg + r * 264 + (lane & 15) * 16);
                *(f16x8*)(dst + (size_t)r * 512 + (lane & 15) * 16) = v;
            }
        }
        asm volatile("s_waitcnt lgkmcnt(0)" ::: "memory");
        __builtin_amdgcn_sched_barrier(0);
    }
    if (lane < 32)
        pml[((size_t)z * BATCH + b) * NTOK + row0 + lane] = make_float2(m, l_full);
}

// ---------------------------------------------------------------------------
// Merge — cc in grid (verified r12) + nontemporal single-use streams
// (ext-vector f32x4 for the nontemporal store; HIP float4 class rejected).
// ---------------------------------------------------------------------------
template <int SEG>
__global__ __launch_bounds__(256) void merge_kernel(
    const _Float16* __restrict__ pacc, const float2* __restrict__ pml,
    float* __restrict__ out)
{
    const int tid = threadIdx.x;
    const int n0 = blockIdx.x * 64;
    const int cc = blockIdx.y;
    const int b  = blockIdx.z;

    __shared__ float wgt[SEG][64];
    __shared__ float dinv[64];
    __shared__ float T[64][68];

    if (tid < 64) {
        int n = n0 + tid;
        float ms[SEG], ls[SEG];
#pragma unroll
        for (int s = 0; s < SEG; ++s) {
            float2 v = pml[((size_t)s * BATCH + b) * NTOK + n];
            ms[s] = v.x; ls[s] = v.y;
        }
        float M = ms[0];
#pragma unroll
        for (int s = 1; s < SEG; ++s) M = fmaxf(M, ms[s]);
        float den = 0.f;
#pragma unroll
        for (int s = 0; s < SEG; ++s) {
            float g = ls[s] * __expf(ms[s] - M);
            wgt[s][tid] = g;
            den += g;
        }
        dinv[tid] = 1.f / den;
    }
    __syncthreads();

    {
        const int nl = tid >> 2, cg = (tid & 3) * 16;
        float a[16];
#pragma unroll
        for (int u = 0; u < 16; ++u) a[u] = 0.f;
#pragma unroll
        for (int s = 0; s < SEG; ++s) {
            const _Float16* p = pacc + (((size_t)s * BATCH + b) * NTOK + n0 + nl) * CDIM
                                + cc * 64 + cg;
            f16x8 v0 = __builtin_nontemporal_load((const f16x8*)p);
            f16x8 v1 = __builtin_nontemporal_load(((const f16x8*)p) + 1);
            float g = wgt[s][nl];
#pragma unroll
            for (int u = 0; u < 8; ++u) {
                a[u]     += g * (float)v0[u];
                a[8 + u] += g * (float)v1[u];
            }
        }
        float di = dinv[nl];
#pragma unroll
        for (int u = 0; u < 16; ++u) T[nl][cg + u] = a[u] * di;
    }
    __syncthreads();
    {
        const int cl = tid >> 2, nb2 = (tid & 3) * 16;
        float* ob = out + ((size_t)b * CDIM + cc * 64 + cl) * NTOK + n0 + nb2;
#pragma unroll
        for (int u = 0; u < 4; ++u) {
            f32x4 v = { T[nb2 + u * 4 + 0][cl], T[nb2 + u * 4 + 1][cl],
                        T[nb2 + u * 4 + 2][cl], T[nb2 + u * 4 + 3][cl] };
            __builtin_nontemporal_store(v, (f32x4*)&ob[u * 4]);
        }
    }
}

// ---------------------------------------------------------------------------
extern "C" void kernel_launch(void* const* d_in, const int* in_sizes, int n_in,
                              void* d_out, int out_size, void* d_ws, size_t ws_size,
                              hipStream_t stream)
{
    const float* x1 = (const float*)d_in[0];
    const float* x2 = (const float*)d_in[1];
    const float* Wq = (const float*)d_in[2];
    const float* bq = (const float*)d_in[3];
    const float* Wk = (const float*)d_in[4];
    const float* bk = (const float*)d_in[5];
    const float* Wv = (const float*)d_in[6];
    const float* bv = (const float*)d_in[7];
    float* out = (float*)d_out;

    const size_t plane = (size_t)BATCH * NTOK * CDIM;   // 4,718,592
    _Float16* ws16 = (_Float16*)d_ws;
    _Float16* Q   = ws16;
    _Float16* K   = ws16 + plane;
    _Float16* Vt  = ws16 + 2 * plane;
    _Float16* Wh  = ws16 + 3 * plane;               // 196608 elems
    const size_t fixed16 = 3 * plane + 196608;

    auto need = [&](size_t S) {
        return fixed16 * 2 + S * plane * 2 + S * (size_t)BATCH * NTOK * 8;
    };
    const int SEG = (ws_size >= need(3)) ? 3 : (ws_size >= need(2)) ? 2 : 1;

    _Float16* pacc = ws16 + fixed16;
    float2*   pml  = (float2*)((char*)d_ws + fixed16 * 2 + (size_t)SEG * plane * 2);

    cast_w<<<dim3(192), dim3(256), 0, stream>>>(Wq, Wk, Wv, Wh);
    proj_mfma<<<dim3(36, 3, BATCH), dim3(256), 0, stream>>>(
        x1, x2, Wh, bq, bk, bv, Q, K, Vt);

    const int nb = 9 * BATCH;
    if (SEG == 3) {
        attn_fa<3><<<dim3(nb * 3), dim3(512), 0, stream>>>(Q, K, Vt, pacc, pml);
        merge_kernel<3><<<dim3(36, 4, BATCH), dim3(256), 0, stream>>>(pacc, pml, out);
    } else if (SEG == 2) {
        attn_fa<2><<<dim3(nb * 2), dim3(512), 0, stream>>>(Q, K, Vt, pacc, pml);
        merge_kernel<2><<<dim3(36, 4, BATCH), dim3(256), 0, stream>>>(pacc, pml, out);
    } else {
        attn_fa<1><<<dim3(nb), dim3(512), 0, stream>>>(Q, K, Vt, pacc, pml);
        merge_kernel<1><<<dim3(36, 4, BATCH), dim3(256), 0, stream>>>(pacc, pml, out);
    }
}

// Round 17
// 128.255 us; speedup vs baseline: 1.0302x; 1.0302x over previous
//
#include <hip/hip_runtime.h>
#include <cfloat>
#include <cstddef>
#include <cstdint>

#define BATCH 8
#define CDIM  256
#define NTOK  2304   // 48*48

typedef float    f32x4  __attribute__((ext_vector_type(4)));
typedef float    f32x16 __attribute__((ext_vector_type(16)));
typedef _Float16 f16x8  __attribute__((ext_vector_type(8)));
typedef _Float16 f16x4  __attribute__((ext_vector_type(4)));

#define MFMA16(a, b, c) __builtin_amdgcn_mfma_f32_16x16x32_f16(a, b, c, 0, 0, 0)
#define MFMA32(a, b, c) __builtin_amdgcn_mfma_f32_32x32x16_f16(a, b, c, 0, 0, 0)

__device__ __forceinline__ void gl_lds16(const void* g, void* l) {
    __builtin_amdgcn_global_load_lds(
        (const __attribute__((address_space(1))) void*)g,
        (__attribute__((address_space(3))) void*)l, 16, 0, 0);
}

// ---------------------------------------------------------------------------
// cast_fused: one launch does both (verified r12/r14)
//   blocks [0,192):   Wq|Wk|Wv fp32 -> Wh fp16 [3][256][256]
//   blocks [192,...): x [B,C,N] fp32 -> Xt [B,N,C] fp16 (64x64 LDS transpose)
// ---------------------------------------------------------------------------
__global__ __launch_bounds__(256) void cast_fused(
    const float* __restrict__ x1, const float* __restrict__ x2,
    const float* __restrict__ Wq, const float* __restrict__ Wk,
    const float* __restrict__ Wv,
    _Float16* __restrict__ Xt1, _Float16* __restrict__ Xt2,
    _Float16* __restrict__ Wh)
{
    const int tid = threadIdx.x;
    int bx = blockIdx.x;

    if (bx < 192) {
        int i = (bx * 256 + tid) * 4;
        const float* src = (i < 65536) ? (Wq + i)
                         : (i < 131072) ? (Wk + (i - 65536)) : (Wv + (i - 131072));
        float4 v = *(const float4*)src;
        f16x4 h = { (_Float16)v.x, (_Float16)v.y, (_Float16)v.z, (_Float16)v.w };
        *(f16x4*)(Wh + i) = h;
        return;
    }
    bx -= 192;
    const int n0 = (bx % 36) * 64;
    const int rest = bx / 36;
    const int c0 = (rest & 3) * 64;
    const int bz = rest >> 2;
    const float* X   = (bz < 8) ? x1 : x2;
    _Float16*   Xt   = (bz < 8) ? Xt1 : Xt2;
    const int b = bz & 7;

    __shared__ _Float16 T[64][72];

    {
        const int cl = tid >> 2, nch = (tid & 3) * 16;
        const float* src = X + (size_t)(b * CDIM + c0 + cl) * NTOK + n0 + nch;
#pragma unroll
        for (int u = 0; u < 4; ++u) {
            float4 v = *(const float4*)(src + u * 4);
            T[cl][nch + u * 4 + 0] = (_Float16)v.x;
            T[cl][nch + u * 4 + 1] = (_Float16)v.y;
            T[cl][nch + u * 4 + 2] = (_Float16)v.z;
            T[cl][nch + u * 4 + 3] = (_Float16)v.w;
        }
    }
    __syncthreads();
    {
        const int nl = tid >> 2, cch = (tid & 3) * 16;
        _Float16* dst = Xt + (size_t)(b * NTOK + n0 + nl) * CDIM + c0 + cch;
        f16x8 o0, o1;
#pragma unroll
        for (int i = 0; i < 8; ++i) {
            o0[i] = T[cch + i][nl];
            o1[i] = T[cch + 8 + i][nl];
        }
        *(f16x8*)dst = o0;
        *(f16x8*)(dst + 8) = o1;
    }
}

// ---------------------------------------------------------------------------
// proj_mfma (verified r12/r14: Xt input, Xl staged once, Wl per chunk)
// ---------------------------------------------------------------------------
__global__ __launch_bounds__(256, 2) void proj_mfma(
    const _Float16* __restrict__ Xt1, const _Float16* __restrict__ Xt2,
    const _Float16* __restrict__ Wh,
    const float* __restrict__ bq, const float* __restrict__ bk,
    const float* __restrict__ bv,
    _Float16* __restrict__ Qo, _Float16* __restrict__ Ko, _Float16* __restrict__ Vo)
{
    const int tid  = threadIdx.x;
    const int lane = tid & 63;
    const int w    = tid >> 6;
    const int l15  = lane & 15, l4 = lane >> 4;
    const int n0   = blockIdx.x * 64;
    const int mode = blockIdx.y;
    const int b    = blockIdx.z;

    const _Float16* Xt = (mode == 0) ? Xt1 : Xt2;
    const _Float16* Wm = Wh + mode * 65536;
    const float* bias  = (mode == 0) ? bq : (mode == 1) ? bk : bv;
    _Float16* OUT      = (mode == 0) ? Qo : (mode == 1) ? Ko : Vo;

    __shared__ __align__(16) char sm[65536];
    _Float16* Xl = (_Float16*)sm;
    _Float16* Wl = (_Float16*)(sm + 32768);

#pragma unroll
    for (int t = 0; t < 8; ++t) {
        int i = w * 8 + t;
        int row = 2 * i + (lane >> 5);
        int ch  = lane & 31;
        gl_lds16(Xt + (size_t)(b * NTOK + n0 + row) * CDIM + ((ch ^ (row & 7)) * 8),
                 (char*)Xl + i * 1024);
    }

    float bias_o[4];
#pragma unroll
    for (int ot = 0; ot < 4; ++ot) bias_o[ot] = bias[w * 64 + ot * 16 + l15];

    f32x4 acc[16];
#pragma unroll
    for (int i = 0; i < 16; ++i) acc[i] = (f32x4){0.f, 0.f, 0.f, 0.f};

    for (int c0 = 0; c0 < CDIM; c0 += 64) {
        __syncthreads();
#pragma unroll
        for (int t = 0; t < 8; ++t) {
            int i = w * 8 + t;
            int row = 8 * i + (lane >> 3);
            int ch  = lane & 7;
            gl_lds16(Wm + (size_t)row * CDIM + c0 + ((ch ^ (row & 7)) * 8),
                     (char*)Wl + i * 1024);
        }
        __syncthreads();

#pragma unroll
        for (int kk2 = 0; kk2 < 2; ++kk2) {
            f16x8 a[4], bf[4];
#pragma unroll
            for (int nt = 0; nt < 4; ++nt) {
                int row = nt * 16 + l15;
                int ch  = ((c0 >> 3) + kk2 * 4 + l4) ^ (row & 7);
                a[nt] = *(const f16x8*)((const char*)Xl + row * 512 + ch * 16);
            }
#pragma unroll
            for (int ot = 0; ot < 4; ++ot) {
                int row = w * 64 + ot * 16 + l15;
                int ch  = (kk2 * 4 + l4) ^ (row & 7);
                bf[ot] = *(const f16x8*)((const char*)Wl + row * 128 + ch * 16);
            }
#pragma unroll
            for (int nt = 0; nt < 4; ++nt)
#pragma unroll
                for (int ot = 0; ot < 4; ++ot)
                    acc[nt * 4 + ot] = MFMA16(a[nt], bf[ot], acc[nt * 4 + ot]);
        }
    }

    __syncthreads();

    if (mode <= 1) {
        _Float16* Dl = (_Float16*)sm;
#pragma unroll
        for (int nt = 0; nt < 4; ++nt)
#pragma unroll
            for (int ot = 0; ot < 4; ++ot)
#pragma unroll
                for (int reg = 0; reg < 4; ++reg)
                    Dl[(nt * 16 + 4 * l4 + reg) * 256 + w * 64 + ot * 16 + l15] =
                        (_Float16)(acc[nt * 4 + ot][reg] + bias_o[ot]);
        __syncthreads();
        char* dst = (char*)(OUT + ((size_t)b * NTOK + n0) * CDIM);
#pragma unroll
        for (int u = 0; u < 8; ++u) {
            f16x8 v = *(const f16x8*)((const char*)Dl + u * 4096 + tid * 16);
            *(f16x8*)(dst + u * 4096 + tid * 16) = v;
        }
    } else {
        _Float16* Dlv = (_Float16*)sm;   // [256][80]
#pragma unroll
        for (int nt = 0; nt < 4; ++nt)
#pragma unroll
            for (int ot = 0; ot < 4; ++ot)
#pragma unroll
                for (int reg = 0; reg < 4; ++reg)
                    Dlv[(w * 64 + ot * 16 + l15) * 80 + nt * 16 + 4 * l4 + reg] =
                        (_Float16)(acc[nt * 4 + ot][reg] + bias_o[ot]);
        __syncthreads();
#pragma unroll
        for (int t = 0; t < 8; ++t) {
            int ro = (w * 8 + t) * 8 + (lane >> 3);
            f16x8 v = *(const f16x8*)((const char*)Dlv + ro * 160 + (lane & 7) * 16);
            *(f16x8*)(OUT + ((size_t)b * CDIM + ro) * NTOK + n0 + (lane & 7) * 8) = v;
        }
    }
}

// ---------------------------------------------------------------------------
// Split-KV flash attention — UNCHANGED from r14 (verified 78.5us):
// 32x32x16 swapped-operand, sigma K-row perm, no P LDS, precomputed staging
// pointers, jb not unrolled, KVBLK=64 dbuf, 128KB LDS.
// ---------------------------------------------------------------------------
template <int SEG>
__global__ __launch_bounds__(512, 2) void attn_fa(
    const _Float16* __restrict__ Q, const _Float16* __restrict__ K,
    const _Float16* __restrict__ Vt, _Float16* __restrict__ pacc,
    float2* __restrict__ pml)
{
    const int tid  = threadIdx.x;
    const int lane = tid & 63;
    const int w    = tid >> 6;
    const int l31  = lane & 31;
    const int h    = lane >> 5;

    const int nb  = 9 * BATCH * SEG, cpx = nb / 8;
    const int bid = blockIdx.x;
    const int swz = (bid & 7) * cpx + (bid >> 3);
    const int x = swz % 9;
    const int b = (swz / 9) & 7;
    const int z = swz / 72;

    const int row0   = x * 256 + w * 32;
    const int jbase  = z * (NTOK / SEG);
    const int NTILES = NTOK / SEG / 64;

    __shared__ __align__(16) char smem[131072];

    const _Float16* kSrc0; const _Float16* kSrc1;
    const _Float16* kSrc2; const _Float16* kSrc3;
    const _Float16* vSrc0; const _Float16* vSrc1;
    const _Float16* vSrc2; const _Float16* vSrc3;
    {
        const size_t kbb = (size_t)b * NTOK;
        const size_t vbb = (size_t)b * CDIM * NTOK;
        const int chunk = lane & 31;
        const int vch   = lane & 7;
        const int vr    = lane >> 3;
#pragma unroll
        for (int t = 0; t < 4; ++t) {
            int i  = w * 4 + t;
            int lr = 2 * i + h;
            int gr = (lr & 51) | ((lr & 4) << 1) | ((lr & 8) >> 1);
            const _Float16* ks =
                K + (kbb + jbase + gr) * CDIM + ((chunk ^ (lr & 7)) * 8);
            int vrow = 8 * i + vr;
            const _Float16* vs =
                Vt + vbb + (size_t)vrow * NTOK + jbase + ((vch ^ (vrow & 7)) * 8);
            if (t == 0) { kSrc0 = ks; vSrc0 = vs; }
            else if (t == 1) { kSrc1 = ks; vSrc1 = vs; }
            else if (t == 2) { kSrc2 = ks; vSrc2 = vs; }
            else { kSrc3 = ks; vSrc3 = vs; }
        }
    }

    f16x8 qa[16];
    {
        const _Float16* qb = Q + ((size_t)b * NTOK + row0 + l31) * CDIM + h * 8;
#pragma unroll
        for (int kk = 0; kk < 16; ++kk)
            qa[kk] = __builtin_nontemporal_load((const f16x8*)(qb + kk * 16));
    }

    f32x16 acc[8];
#pragma unroll
    for (int cb = 0; cb < 8; ++cb)
#pragma unroll
        for (int e = 0; e < 16; ++e) acc[cb][e] = 0.f;
    float m  = -FLT_MAX;
    float ps = 0.f;

    const int ldsDstK = w * 4096;
    const int ldsDstV = 32768 + w * 4096;

    auto stage = [&](int buf) {
        char* base = smem + buf * 65536;
        gl_lds16(kSrc0, base + ldsDstK);
        gl_lds16(kSrc1, base + ldsDstK + 1024);
        gl_lds16(kSrc2, base + ldsDstK + 2048);
        gl_lds16(kSrc3, base + ldsDstK + 3072);
        gl_lds16(vSrc0, base + ldsDstV);
        gl_lds16(vSrc1, base + ldsDstV + 1024);
        gl_lds16(vSrc2, base + ldsDstV + 2048);
        gl_lds16(vSrc3, base + ldsDstV + 3072);
        kSrc0 += 64 * CDIM; kSrc1 += 64 * CDIM;
        kSrc2 += 64 * CDIM; kSrc3 += 64 * CDIM;
        vSrc0 += 64; vSrc1 += 64; vSrc2 += 64; vSrc3 += 64;
    };

    stage(0);
    __syncthreads();

    const int xs = l31 & 7;

    for (int jt = 0; jt < NTILES; ++jt) {
        const int cur = jt & 1;

        if (jt + 1 < NTILES) stage(cur ^ 1);

        const char* Klc = (const char*)smem + cur * 65536;
        const char* Vlc = Klc + 32768;

#pragma unroll 1
        for (int jb = 0; jb < 2; ++jb) {
            f32x16 s;
#pragma unroll
            for (int e = 0; e < 16; ++e) s[e] = 0.f;
            const char* kb = Klc + (jb * 32 + l31) * 512;
#pragma unroll
            for (int kk = 0; kk < 16; ++kk) {
                f16x8 kf = *(const f16x8*)(kb + (((kk * 2 + h) ^ xs) * 16));
                s = MFMA32(kf, qa[kk], s);
            }

            float pm = s[0];
#pragma unroll
            for (int e = 1; e < 16; ++e) pm = fmaxf(pm, s[e]);
            pm = fmaxf(pm, __shfl_xor(pm, 32));
            if (pm > m + 8.f) {
                float sc = __expf(m - pm);
                m = pm;
                ps *= sc;
#pragma unroll
                for (int cb = 0; cb < 8; ++cb)
#pragma unroll
                    for (int e = 0; e < 16; ++e) acc[cb][e] *= sc;
            }

            f16x8 pa0, pa1;
#pragma unroll
            for (int e = 0; e < 8; ++e) {
                float p0 = __expf(s[e] - m);
                float p1 = __expf(s[8 + e] - m);
                ps += p0 + p1;
                pa0[e] = (_Float16)p0;
                pa1[e] = (_Float16)p1;
            }

            const int o0 = ((jb * 4 + 0 + h) ^ xs) * 16;
            const int o1 = ((jb * 4 + 2 + h) ^ xs) * 16;
#pragma unroll
            for (int cb = 0; cb < 8; ++cb) {
                const char* vb0 = Vlc + (cb * 32 + l31) * 128;
                f16x8 v0 = *(const f16x8*)(vb0 + o0);
                acc[cb] = MFMA32(v0, pa0, acc[cb]);
                f16x8 v1 = *(const f16x8*)(vb0 + o1);
                acc[cb] = MFMA32(v1, pa1, acc[cb]);
            }
        }

        __syncthreads();
    }

    float l_full = ps + __shfl_xor(ps, 32);
    float inv = 1.f / l_full;
    const size_t pbase = ((size_t)z * BATCH + b) * NTOK * CDIM;
    _Float16* stg = (_Float16*)(smem + w * 8448);

#pragma unroll
    for (int pass = 0; pass < 2; ++pass) {
#pragma unroll
        for (int cb4 = 0; cb4 < 4; ++cb4) {
            const f32x16 a = acc[pass * 4 + cb4];
#pragma unroll
            for (int g = 0; g < 4; ++g) {
                f16x4 o = { (_Float16)(a[4 * g + 0] * inv),
                            (_Float16)(a[4 * g + 1] * inv),
                            (_Float16)(a[4 * g + 2] * inv),
                            (_Float16)(a[4 * g + 3] * inv) };
                *(f16x4*)&stg[l31 * 132 + cb4 * 32 + g * 8 + h * 4] = o;
            }
        }
        asm volatile("s_waitcnt lgkmcnt(0)" ::: "memory");
        __builtin_amdgcn_sched_barrier(0);
        {
            char* dst = (char*)(pacc + pbase + (size_t)row0 * CDIM) + pass * 256;
#pragma unroll
            for (int u = 0; u < 8; ++u) {
                int r = u * 4 + (lane >> 4);
                f16x8 v = *(const f16x8*)((const char*)stg + r * 264 + (lane & 15) * 16);
                *(f16x8*)(dst + (size_t)r * 512 + (lane & 15) * 16) = v;
            }
        }
        asm volatile("s_waitcnt lgkmcnt(0)" ::: "memory");
        __builtin_amdgcn_sched_barrier(0);
    }
    if (lane < 32)
        pml[((size_t)z * BATCH + b) * NTOK + row0 + lane] = make_float2(m, l_full);
}

// ---------------------------------------------------------------------------
// Merge — cc in grid + nontemporal single-use streams (f32x4 ext-vector).
// ---------------------------------------------------------------------------
template <int SEG>
__global__ __launch_bounds__(256) void merge_kernel(
    const _Float16* __restrict__ pacc, const float2* __restrict__ pml,
    float* __restrict__ out)
{
    const int tid = threadIdx.x;
    const int n0 = blockIdx.x * 64;
    const int cc = blockIdx.y;
    const int b  = blockIdx.z;

    __shared__ float wgt[SEG][64];
    __shared__ float dinv[64];
    __shared__ float T[64][68];

    if (tid < 64) {
        int n = n0 + tid;
        float ms[SEG], ls[SEG];
#pragma unroll
        for (int s = 0; s < SEG; ++s) {
            float2 v = pml[((size_t)s * BATCH + b) * NTOK + n];
            ms[s] = v.x; ls[s] = v.y;
        }
        float M = ms[0];
#pragma unroll
        for (int s = 1; s < SEG; ++s) M = fmaxf(M, ms[s]);
        float den = 0.f;
#pragma unroll
        for (int s = 0; s < SEG; ++s) {
            float g = ls[s] * __expf(ms[s] - M);
            wgt[s][tid] = g;
            den += g;
        }
        dinv[tid] = 1.f / den;
    }
    __syncthreads();

    {
        const int nl = tid >> 2, cg = (tid & 3) * 16;
        float a[16];
#pragma unroll
        for (int u = 0; u < 16; ++u) a[u] = 0.f;
#pragma unroll
        for (int s = 0; s < SEG; ++s) {
            const _Float16* p = pacc + (((size_t)s * BATCH + b) * NTOK + n0 + nl) * CDIM
                                + cc * 64 + cg;
            f16x8 v0 = __builtin_nontemporal_load((const f16x8*)p);
            f16x8 v1 = __builtin_nontemporal_load(((const f16x8*)p) + 1);
            float g = wgt[s][nl];
#pragma unroll
            for (int u = 0; u < 8; ++u) {
                a[u]     += g * (float)v0[u];
                a[8 + u] += g * (float)v1[u];
            }
        }
        float di = dinv[nl];
#pragma unroll
        for (int u = 0; u < 16; ++u) T[nl][cg + u] = a[u] * di;
    }
    __syncthreads();
    {
        const int cl = tid >> 2, nb2 = (tid & 3) * 16;
        float* ob = out + ((size_t)b * CDIM + cc * 64 + cl) * NTOK + n0 + nb2;
#pragma unroll
        for (int u = 0; u < 4; ++u) {
            f32x4 v = { T[nb2 + u * 4 + 0][cl], T[nb2 + u * 4 + 1][cl],
                        T[nb2 + u * 4 + 2][cl], T[nb2 + u * 4 + 3][cl] };
            __builtin_nontemporal_store(v, (f32x4*)&ob[u * 4]);
        }
    }
}

// ---------------------------------------------------------------------------
extern "C" void kernel_launch(void* const* d_in, const int* in_sizes, int n_in,
                              void* d_out, int out_size, void* d_ws, size_t ws_size,
                              hipStream_t stream)
{
    const float* x1 = (const float*)d_in[0];
    const float* x2 = (const float*)d_in[1];
    const float* Wq = (const float*)d_in[2];
    const float* bq = (const float*)d_in[3];
    const float* Wk = (const float*)d_in[4];
    const float* bk = (const float*)d_in[5];
    const float* Wv = (const float*)d_in[6];
    const float* bv = (const float*)d_in[7];
    float* out = (float*)d_out;

    const size_t plane = (size_t)BATCH * NTOK * CDIM;   // 4,718,592
    _Float16* ws16 = (_Float16*)d_ws;
    _Float16* Q   = ws16;
    _Float16* K   = ws16 + plane;
    _Float16* Vt  = ws16 + 2 * plane;
    _Float16* Xt1 = ws16 + 3 * plane;
    _Float16* Xt2 = ws16 + 4 * plane;
    _Float16* Wh  = ws16 + 5 * plane;
    const size_t fixed16 = 5 * plane + 196608;

    auto need = [&](size_t S) {
        return fixed16 * 2 + S * plane * 2 + S * (size_t)BATCH * NTOK * 8;
    };
    const int SEG = (ws_size >= need(3)) ? 3 : (ws_size >= need(2)) ? 2 : 1;

    _Float16* pacc = ws16 + fixed16;
    float2*   pml  = (float2*)((char*)d_ws + fixed16 * 2 + (size_t)SEG * plane * 2);

    cast_fused<<<dim3(192 + 36 * 4 * 16), dim3(256), 0, stream>>>(
        x1, x2, Wq, Wk, Wv, Xt1, Xt2, Wh);
    proj_mfma<<<dim3(36, 3, BATCH), dim3(256), 0, stream>>>(
        Xt1, Xt2, Wh, bq, bk, bv, Q, K, Vt);

    const int nb = 9 * BATCH;
    if (SEG == 3) {
        attn_fa<3><<<dim3(nb * 3), dim3(512), 0, stream>>>(Q, K, Vt, pacc, pml);
        merge_kernel<3><<<dim3(36, 4, BATCH), dim3(256), 0, stream>>>(pacc, pml, out);
    } else if (SEG == 2) {
        attn_fa<2><<<dim3(nb * 2), dim3(512), 0, stream>>>(Q, K, Vt, pacc, pml);
        merge_kernel<2><<<dim3(36, 4, BATCH), dim3(256), 0, stream>>>(pacc, pml, out);
    } else {
        attn_fa<1><<<dim3(nb), dim3(512), 0, stream>>>(Q, K, Vt, pacc, pml);
        merge_kernel<1><<<dim3(36, 4, BATCH), dim3(256), 0, stream>>>(pacc, pml, out);
    }
}

// Round 18
// 114.630 us; speedup vs baseline: 1.1526x; 1.1189x over previous
//
#include <hip/hip_runtime.h>
#include <cfloat>
#include <cstddef>
#include <cstdint>

#define BATCH 8
#define CDIM  256
#define NTOK  2304   // 48*48

typedef float    f32x4  __attribute__((ext_vector_type(4)));
typedef float    f32x16 __attribute__((ext_vector_type(16)));
typedef _Float16 f16x8  __attribute__((ext_vector_type(8)));
typedef _Float16 f16x4  __attribute__((ext_vector_type(4)));

#define MFMA16(a, b, c) __builtin_amdgcn_mfma_f32_16x16x32_f16(a, b, c, 0, 0, 0)
#define MFMA32(a, b, c) __builtin_amdgcn_mfma_f32_32x32x16_f16(a, b, c, 0, 0, 0)

__device__ __forceinline__ void gl_lds16(const void* g, void* l) {
    __builtin_amdgcn_global_load_lds(
        (const __attribute__((address_space(1))) void*)g,
        (__attribute__((address_space(3))) void*)l, 16, 0, 0);
}

// ---------------------------------------------------------------------------
// cast_fused: one launch does both (verified r12/r14)
//   blocks [0,192):   Wq|Wk|Wv fp32 -> Wh fp16 [3][256][256]
//   blocks [192,...): x [B,C,N] fp32 -> Xt [B,N,C] fp16 (64x64 LDS transpose)
// ---------------------------------------------------------------------------
__global__ __launch_bounds__(256) void cast_fused(
    const float* __restrict__ x1, const float* __restrict__ x2,
    const float* __restrict__ Wq, const float* __restrict__ Wk,
    const float* __restrict__ Wv,
    _Float16* __restrict__ Xt1, _Float16* __restrict__ Xt2,
    _Float16* __restrict__ Wh)
{
    const int tid = threadIdx.x;
    int bx = blockIdx.x;

    if (bx < 192) {
        int i = (bx * 256 + tid) * 4;
        const float* src = (i < 65536) ? (Wq + i)
                         : (i < 131072) ? (Wk + (i - 65536)) : (Wv + (i - 131072));
        float4 v = *(const float4*)src;
        f16x4 h = { (_Float16)v.x, (_Float16)v.y, (_Float16)v.z, (_Float16)v.w };
        *(f16x4*)(Wh + i) = h;
        return;
    }
    bx -= 192;
    const int n0 = (bx % 36) * 64;
    const int rest = bx / 36;
    const int c0 = (rest & 3) * 64;
    const int bz = rest >> 2;
    const float* X   = (bz < 8) ? x1 : x2;
    _Float16*   Xt   = (bz < 8) ? Xt1 : Xt2;
    const int b = bz & 7;

    __shared__ _Float16 T[64][72];

    {
        const int cl = tid >> 2, nch = (tid & 3) * 16;
        const float* src = X + (size_t)(b * CDIM + c0 + cl) * NTOK + n0 + nch;
#pragma unroll
        for (int u = 0; u < 4; ++u) {
            float4 v = *(const float4*)(src + u * 4);
            T[cl][nch + u * 4 + 0] = (_Float16)v.x;
            T[cl][nch + u * 4 + 1] = (_Float16)v.y;
            T[cl][nch + u * 4 + 2] = (_Float16)v.z;
            T[cl][nch + u * 4 + 3] = (_Float16)v.w;
        }
    }
    __syncthreads();
    {
        const int nl = tid >> 2, cch = (tid & 3) * 16;
        _Float16* dst = Xt + (size_t)(b * NTOK + n0 + nl) * CDIM + c0 + cch;
        f16x8 o0, o1;
#pragma unroll
        for (int i = 0; i < 8; ++i) {
            o0[i] = T[cch + i][nl];
            o1[i] = T[cch + 8 + i][nl];
        }
        *(f16x8*)dst = o0;
        *(f16x8*)(dst + 8) = o1;
    }
}

// ---------------------------------------------------------------------------
// proj_mfma (verified r12/r14: Xt input, Xl staged once, Wl per chunk)
// ---------------------------------------------------------------------------
__global__ __launch_bounds__(256, 2) void proj_mfma(
    const _Float16* __restrict__ Xt1, const _Float16* __restrict__ Xt2,
    const _Float16* __restrict__ Wh,
    const float* __restrict__ bq, const float* __restrict__ bk,
    const float* __restrict__ bv,
    _Float16* __restrict__ Qo, _Float16* __restrict__ Ko, _Float16* __restrict__ Vo)
{
    const int tid  = threadIdx.x;
    const int lane = tid & 63;
    const int w    = tid >> 6;
    const int l15  = lane & 15, l4 = lane >> 4;
    const int n0   = blockIdx.x * 64;
    const int mode = blockIdx.y;
    const int b    = blockIdx.z;

    const _Float16* Xt = (mode == 0) ? Xt1 : Xt2;
    const _Float16* Wm = Wh + mode * 65536;
    const float* bias  = (mode == 0) ? bq : (mode == 1) ? bk : bv;
    _Float16* OUT      = (mode == 0) ? Qo : (mode == 1) ? Ko : Vo;

    __shared__ __align__(16) char sm[65536];
    _Float16* Xl = (_Float16*)sm;
    _Float16* Wl = (_Float16*)(sm + 32768);

#pragma unroll
    for (int t = 0; t < 8; ++t) {
        int i = w * 8 + t;
        int row = 2 * i + (lane >> 5);
        int ch  = lane & 31;
        gl_lds16(Xt + (size_t)(b * NTOK + n0 + row) * CDIM + ((ch ^ (row & 7)) * 8),
                 (char*)Xl + i * 1024);
    }

    float bias_o[4];
#pragma unroll
    for (int ot = 0; ot < 4; ++ot) bias_o[ot] = bias[w * 64 + ot * 16 + l15];

    f32x4 acc[16];
#pragma unroll
    for (int i = 0; i < 16; ++i) acc[i] = (f32x4){0.f, 0.f, 0.f, 0.f};

    for (int c0 = 0; c0 < CDIM; c0 += 64) {
        __syncthreads();
#pragma unroll
        for (int t = 0; t < 8; ++t) {
            int i = w * 8 + t;
            int row = 8 * i + (lane >> 3);
            int ch  = lane & 7;
            gl_lds16(Wm + (size_t)row * CDIM + c0 + ((ch ^ (row & 7)) * 8),
                     (char*)Wl + i * 1024);
        }
        __syncthreads();

#pragma unroll
        for (int kk2 = 0; kk2 < 2; ++kk2) {
            f16x8 a[4], bf[4];
#pragma unroll
            for (int nt = 0; nt < 4; ++nt) {
                int row = nt * 16 + l15;
                int ch  = ((c0 >> 3) + kk2 * 4 + l4) ^ (row & 7);
                a[nt] = *(const f16x8*)((const char*)Xl + row * 512 + ch * 16);
            }
#pragma unroll
            for (int ot = 0; ot < 4; ++ot) {
                int row = w * 64 + ot * 16 + l15;
                int ch  = (kk2 * 4 + l4) ^ (row & 7);
                bf[ot] = *(const f16x8*)((const char*)Wl + row * 128 + ch * 16);
            }
#pragma unroll
            for (int nt = 0; nt < 4; ++nt)
#pragma unroll
                for (int ot = 0; ot < 4; ++ot)
                    acc[nt * 4 + ot] = MFMA16(a[nt], bf[ot], acc[nt * 4 + ot]);
        }
    }

    __syncthreads();

    if (mode <= 1) {
        _Float16* Dl = (_Float16*)sm;
#pragma unroll
        for (int nt = 0; nt < 4; ++nt)
#pragma unroll
            for (int ot = 0; ot < 4; ++ot)
#pragma unroll
                for (int reg = 0; reg < 4; ++reg)
                    Dl[(nt * 16 + 4 * l4 + reg) * 256 + w * 64 + ot * 16 + l15] =
                        (_Float16)(acc[nt * 4 + ot][reg] + bias_o[ot]);
        __syncthreads();
        char* dst = (char*)(OUT + ((size_t)b * NTOK + n0) * CDIM);
#pragma unroll
        for (int u = 0; u < 8; ++u) {
            f16x8 v = *(const f16x8*)((const char*)Dl + u * 4096 + tid * 16);
            *(f16x8*)(dst + u * 4096 + tid * 16) = v;
        }
    } else {
        _Float16* Dlv = (_Float16*)sm;   // [256][80]
#pragma unroll
        for (int nt = 0; nt < 4; ++nt)
#pragma unroll
            for (int ot = 0; ot < 4; ++ot)
#pragma unroll
                for (int reg = 0; reg < 4; ++reg)
                    Dlv[(w * 64 + ot * 16 + l15) * 80 + nt * 16 + 4 * l4 + reg] =
                        (_Float16)(acc[nt * 4 + ot][reg] + bias_o[ot]);
        __syncthreads();
#pragma unroll
        for (int t = 0; t < 8; ++t) {
            int ro = (w * 8 + t) * 8 + (lane >> 3);
            f16x8 v = *(const f16x8*)((const char*)Dlv + ro * 160 + (lane & 7) * 16);
            *(f16x8*)(OUT + ((size_t)b * CDIM + ro) * NTOK + n0 + (lane & 7) * 8) = v;
        }
    }
}

// ---------------------------------------------------------------------------
// Split-KV flash attention — UNCHANGED from r14 (verified 78.5us):
// 32x32x16 swapped-operand, sigma K-row perm, no P LDS, precomputed staging
// pointers, jb not unrolled, KVBLK=64 dbuf, 128KB LDS.
// ---------------------------------------------------------------------------
template <int SEG>
__global__ __launch_bounds__(512, 2) void attn_fa(
    const _Float16* __restrict__ Q, const _Float16* __restrict__ K,
    const _Float16* __restrict__ Vt, _Float16* __restrict__ pacc,
    float2* __restrict__ pml)
{
    const int tid  = threadIdx.x;
    const int lane = tid & 63;
    const int w    = tid >> 6;
    const int l31  = lane & 31;
    const int h    = lane >> 5;

    const int nb  = 9 * BATCH * SEG, cpx = nb / 8;
    const int bid = blockIdx.x;
    const int swz = (bid & 7) * cpx + (bid >> 3);
    const int x = swz % 9;
    const int b = (swz / 9) & 7;
    const int z = swz / 72;

    const int row0   = x * 256 + w * 32;
    const int jbase  = z * (NTOK / SEG);
    const int NTILES = NTOK / SEG / 64;

    __shared__ __align__(16) char smem[131072];

    const _Float16* kSrc0; const _Float16* kSrc1;
    const _Float16* kSrc2; const _Float16* kSrc3;
    const _Float16* vSrc0; const _Float16* vSrc1;
    const _Float16* vSrc2; const _Float16* vSrc3;
    {
        const size_t kbb = (size_t)b * NTOK;
        const size_t vbb = (size_t)b * CDIM * NTOK;
        const int chunk = lane & 31;
        const int vch   = lane & 7;
        const int vr    = lane >> 3;
#pragma unroll
        for (int t = 0; t < 4; ++t) {
            int i  = w * 4 + t;
            int lr = 2 * i + h;
            int gr = (lr & 51) | ((lr & 4) << 1) | ((lr & 8) >> 1);
            const _Float16* ks =
                K + (kbb + jbase + gr) * CDIM + ((chunk ^ (lr & 7)) * 8);
            int vrow = 8 * i + vr;
            const _Float16* vs =
                Vt + vbb + (size_t)vrow * NTOK + jbase + ((vch ^ (vrow & 7)) * 8);
            if (t == 0) { kSrc0 = ks; vSrc0 = vs; }
            else if (t == 1) { kSrc1 = ks; vSrc1 = vs; }
            else if (t == 2) { kSrc2 = ks; vSrc2 = vs; }
            else { kSrc3 = ks; vSrc3 = vs; }
        }
    }

    f16x8 qa[16];
    {
        const _Float16* qb = Q + ((size_t)b * NTOK + row0 + l31) * CDIM + h * 8;
#pragma unroll
        for (int kk = 0; kk < 16; ++kk)
            qa[kk] = __builtin_nontemporal_load((const f16x8*)(qb + kk * 16));
    }

    f32x16 acc[8];
#pragma unroll
    for (int cb = 0; cb < 8; ++cb)
#pragma unroll
        for (int e = 0; e < 16; ++e) acc[cb][e] = 0.f;
    float m  = -FLT_MAX;
    float ps = 0.f;

    const int ldsDstK = w * 4096;
    const int ldsDstV = 32768 + w * 4096;

    auto stage = [&](int buf) {
        char* base = smem + buf * 65536;
        gl_lds16(kSrc0, base + ldsDstK);
        gl_lds16(kSrc1, base + ldsDstK + 1024);
        gl_lds16(kSrc2, base + ldsDstK + 2048);
        gl_lds16(kSrc3, base + ldsDstK + 3072);
        gl_lds16(vSrc0, base + ldsDstV);
        gl_lds16(vSrc1, base + ldsDstV + 1024);
        gl_lds16(vSrc2, base + ldsDstV + 2048);
        gl_lds16(vSrc3, base + ldsDstV + 3072);
        kSrc0 += 64 * CDIM; kSrc1 += 64 * CDIM;
        kSrc2 += 64 * CDIM; kSrc3 += 64 * CDIM;
        vSrc0 += 64; vSrc1 += 64; vSrc2 += 64; vSrc3 += 64;
    };

    stage(0);
    __syncthreads();

    const int xs = l31 & 7;

    for (int jt = 0; jt < NTILES; ++jt) {
        const int cur = jt & 1;

        if (jt + 1 < NTILES) stage(cur ^ 1);

        const char* Klc = (const char*)smem + cur * 65536;
        const char* Vlc = Klc + 32768;

#pragma unroll 1
        for (int jb = 0; jb < 2; ++jb) {
            f32x16 s;
#pragma unroll
            for (int e = 0; e < 16; ++e) s[e] = 0.f;
            const char* kb = Klc + (jb * 32 + l31) * 512;
#pragma unroll
            for (int kk = 0; kk < 16; ++kk) {
                f16x8 kf = *(const f16x8*)(kb + (((kk * 2 + h) ^ xs) * 16));
                s = MFMA32(kf, qa[kk], s);
            }

            float pm = s[0];
#pragma unroll
            for (int e = 1; e < 16; ++e) pm = fmaxf(pm, s[e]);
            pm = fmaxf(pm, __shfl_xor(pm, 32));
            if (pm > m + 8.f) {
                float sc = __expf(m - pm);
                m = pm;
                ps *= sc;
#pragma unroll
                for (int cb = 0; cb < 8; ++cb)
#pragma unroll
                    for (int e = 0; e < 16; ++e) acc[cb][e] *= sc;
            }

            f16x8 pa0, pa1;
#pragma unroll
            for (int e = 0; e < 8; ++e) {
                float p0 = __expf(s[e] - m);
                float p1 = __expf(s[8 + e] - m);
                ps += p0 + p1;
                pa0[e] = (_Float16)p0;
                pa1[e] = (_Float16)p1;
            }

            const int o0 = ((jb * 4 + 0 + h) ^ xs) * 16;
            const int o1 = ((jb * 4 + 2 + h) ^ xs) * 16;
#pragma unroll
            for (int cb = 0; cb < 8; ++cb) {
                const char* vb0 = Vlc + (cb * 32 + l31) * 128;
                f16x8 v0 = *(const f16x8*)(vb0 + o0);
                acc[cb] = MFMA32(v0, pa0, acc[cb]);
                f16x8 v1 = *(const f16x8*)(vb0 + o1);
                acc[cb] = MFMA32(v1, pa1, acc[cb]);
            }
        }

        __syncthreads();
    }

    float l_full = ps + __shfl_xor(ps, 32);
    float inv = 1.f / l_full;
    const size_t pbase = ((size_t)z * BATCH + b) * NTOK * CDIM;
    _Float16* stg = (_Float16*)(smem + w * 8448);

#pragma unroll
    for (int pass = 0; pass < 2; ++pass) {
#pragma unroll
        for (int cb4 = 0; cb4 < 4; ++cb4) {
            const f32x16 a = acc[pass * 4 + cb4];
#pragma unroll
            for (int g = 0; g < 4; ++g) {
                f16x4 o = { (_Float16)(a[4 * g + 0] * inv),
                            (_Float16)(a[4 * g + 1] * inv),
                            (_Float16)(a[4 * g + 2] * inv),
                            (_Float16)(a[4 * g + 3] * inv) };
                *(f16x4*)&stg[l31 * 132 + cb4 * 32 + g * 8 + h * 4] = o;
            }
        }
        asm volatile("s_waitcnt lgkmcnt(0)" ::: "memory");
        __builtin_amdgcn_sched_barrier(0);
        {
            char* dst = (char*)(pacc + pbase + (size_t)row0 * CDIM) + pass * 256;
#pragma unroll
            for (int u = 0; u < 8; ++u) {
                int r = u * 4 + (lane >> 4);
                f16x8 v = *(const f16x8*)((const char*)stg + r * 264 + (lane & 15) * 16);
                *(f16x8*)(dst + (size_t)r * 512 + (lane & 15) * 16) = v;
            }
        }
        asm volatile("s_waitcnt lgkmcnt(0)" ::: "memory");
        __builtin_amdgcn_sched_barrier(0);
    }
    if (lane < 32)
        pml[((size_t)z * BATCH + b) * NTOK + row0 + lane] = make_float2(m, l_full);
}

// ---------------------------------------------------------------------------
// Merge — cc in grid, plain cached loads/stores (r14 verified; NT regressed).
// ---------------------------------------------------------------------------
template <int SEG>
__global__ __launch_bounds__(256) void merge_kernel(
    const _Float16* __restrict__ pacc, const float2* __restrict__ pml,
    float* __restrict__ out)
{
    const int tid = threadIdx.x;
    const int n0 = blockIdx.x * 64;
    const int cc = blockIdx.y;
    const int b  = blockIdx.z;

    __shared__ float wgt[SEG][64];
    __shared__ float dinv[64];
    __shared__ float T[64][68];

    if (tid < 64) {
        int n = n0 + tid;
        float ms[SEG], ls[SEG];
#pragma unroll
        for (int s = 0; s < SEG; ++s) {
            float2 v = pml[((size_t)s * BATCH + b) * NTOK + n];
            ms[s] = v.x; ls[s] = v.y;
        }
        float M = ms[0];
#pragma unroll
        for (int s = 1; s < SEG; ++s) M = fmaxf(M, ms[s]);
        float den = 0.f;
#pragma unroll
        for (int s = 0; s < SEG; ++s) {
            float g = ls[s] * __expf(ms[s] - M);
            wgt[s][tid] = g;
            den += g;
        }
        dinv[tid] = 1.f / den;
    }
    __syncthreads();

    {
        const int nl = tid >> 2, cg = (tid & 3) * 16;
        float a[16];
#pragma unroll
        for (int u = 0; u < 16; ++u) a[u] = 0.f;
#pragma unroll
        for (int s = 0; s < SEG; ++s) {
            const _Float16* p = pacc + (((size_t)s * BATCH + b) * NTOK + n0 + nl) * CDIM
                                + cc * 64 + cg;
            f16x8 v0 = ((const f16x8*)p)[0];
            f16x8 v1 = ((const f16x8*)p)[1];
            float g = wgt[s][nl];
#pragma unroll
            for (int u = 0; u < 8; ++u) {
                a[u]     += g * (float)v0[u];
                a[8 + u] += g * (float)v1[u];
            }
        }
        float di = dinv[nl];
#pragma unroll
        for (int u = 0; u < 16; ++u) T[nl][cg + u] = a[u] * di;
    }
    __syncthreads();
    {
        const int cl = tid >> 2, nb2 = (tid & 3) * 16;
        float* ob = out + ((size_t)b * CDIM + cc * 64 + cl) * NTOK + n0 + nb2;
#pragma unroll
        for (int u = 0; u < 4; ++u) {
            float4 v = { T[nb2 + u * 4 + 0][cl], T[nb2 + u * 4 + 1][cl],
                         T[nb2 + u * 4 + 2][cl], T[nb2 + u * 4 + 3][cl] };
            *(float4*)&ob[u * 4] = v;
        }
    }
}

// ---------------------------------------------------------------------------
extern "C" void kernel_launch(void* const* d_in, const int* in_sizes, int n_in,
                              void* d_out, int out_size, void* d_ws, size_t ws_size,
                              hipStream_t stream)
{
    const float* x1 = (const float*)d_in[0];
    const float* x2 = (const float*)d_in[1];
    const float* Wq = (const float*)d_in[2];
    const float* bq = (const float*)d_in[3];
    const float* Wk = (const float*)d_in[4];
    const float* bk = (const float*)d_in[5];
    const float* Wv = (const float*)d_in[6];
    const float* bv = (const float*)d_in[7];
    float* out = (float*)d_out;

    const size_t plane = (size_t)BATCH * NTOK * CDIM;   // 4,718,592
    _Float16* ws16 = (_Float16*)d_ws;
    _Float16* Q   = ws16;
    _Float16* K   = ws16 + plane;
    _Float16* Vt  = ws16 + 2 * plane;
    _Float16* Xt1 = ws16 + 3 * plane;
    _Float16* Xt2 = ws16 + 4 * plane;
    _Float16* Wh  = ws16 + 5 * plane;
    const size_t fixed16 = 5 * plane + 196608;

    auto need = [&](size_t S) {
        return fixed16 * 2 + S * plane * 2 + S * (size_t)BATCH * NTOK * 8;
    };
    const int SEG = (ws_size >= need(3)) ? 3 : (ws_size >= need(2)) ? 2 : 1;

    _Float16* pacc = ws16 + fixed16;
    float2*   pml  = (float2*)((char*)d_ws + fixed16 * 2 + (size_t)SEG * plane * 2);

    cast_fused<<<dim3(192 + 36 * 4 * 16), dim3(256), 0, stream>>>(
        x1, x2, Wq, Wk, Wv, Xt1, Xt2, Wh);
    proj_mfma<<<dim3(36, 3, BATCH), dim3(256), 0, stream>>>(
        Xt1, Xt2, Wh, bq, bk, bv, Q, K, Vt);

    const int nb = 9 * BATCH;
    if (SEG == 3) {
        attn_fa<3><<<dim3(nb * 3), dim3(512), 0, stream>>>(Q, K, Vt, pacc, pml);
        merge_kernel<3><<<dim3(36, 4, BATCH), dim3(256), 0, stream>>>(pacc, pml, out);
    } else if (SEG == 2) {
        attn_fa<2><<<dim3(nb * 2), dim3(512), 0, stream>>>(Q, K, Vt, pacc, pml);
        merge_kernel<2><<<dim3(36, 4, BATCH), dim3(256), 0, stream>>>(pacc, pml, out);
    } else {
        attn_fa<1><<<dim3(nb), dim3(512), 0, stream>>>(Q, K, Vt, pacc, pml);
        merge_kernel<1><<<dim3(36, 4, BATCH), dim3(256), 0, stream>>>(pacc, pml, out);
    }
}